// Round 11
// baseline (284.189 us; speedup 1.0000x reference)
//
#include <hip/hip_runtime.h>

#define T_SEQ  2048
#define JP     2080                       // padded key length (zeroed pads)
#define SL_F    0.12751744f               // SCALE * log2(e)
#define THR_L2  11.0f                     // defer-max threshold (log2 domain)

typedef __attribute__((ext_vector_type(8))) short short8;
typedef __attribute__((ext_vector_type(4))) float f32x4;
typedef __attribute__((ext_vector_type(4))) int   i32x4;

__device__ __forceinline__ unsigned short f2bf(float f) {
  unsigned int u = __float_as_uint(f);
  u += 0x7fff + ((u >> 16) & 1);          // round-to-nearest-even
  return (unsigned short)(u >> 16);
}

// async global->LDS 16B copy: LDS dest = wave-uniform base + lane*16
__device__ __forceinline__ void gload16(const void* g, void* l) {
  __builtin_amdgcn_global_load_lds(
      (const __attribute__((address_space(1))) void*)g,
      (__attribute__((address_space(3))) void*)l, 16, 0, 0);
}

// ---------------------------------------------------------------------------
// quant3: per-row int16 quantization of x, Wa, Wp in ONE launch.
// Row value ~= scale * (nh*256 + nl), |n| <= 32512; i8 hi/lo planes + scale.
// ---------------------------------------------------------------------------
__global__ __launch_bounds__(256) void quant3(
    const float* __restrict__ sx, signed char* __restrict__ dx, float* __restrict__ scx,
    const float* __restrict__ sa, signed char* __restrict__ da, float* __restrict__ sca,
    const float* __restrict__ sp, signed char* __restrict__ dp, float* __restrict__ scp) {
  __shared__ float red[4];
  int r = blockIdx.x;
  const float* s; signed char* d; float* sc; int p;
  if (r < 2048)      { s = sx; d = dx; sc = scx; p = 4194304; }
  else if (r < 5120) { r -= 2048; s = sa; d = da; sc = sca; p = 6291456; }
  else               { r -= 5120; s = sp; d = dp; sc = scp; p = 4194304; }
  const int tid = threadIdx.x;
  const float4* spv = (const float4*)(s + (size_t)r * 2048) + tid * 2;
  float4 v0 = spv[0], v1 = spv[1];
  float vv[8] = {v0.x, v0.y, v0.z, v0.w, v1.x, v1.y, v1.z, v1.w};
  float am = 0.f;
#pragma unroll
  for (int e = 0; e < 8; ++e) am = fmaxf(am, fabsf(vv[e]));
#pragma unroll
  for (int o = 1; o <= 32; o <<= 1) am = fmaxf(am, __shfl_xor(am, o, 64));
  if ((tid & 63) == 0) red[tid >> 6] = am;
  __syncthreads();
  am = fmaxf(fmaxf(red[0], red[1]), fmaxf(red[2], red[3]));
  const float inv = (am > 1e-30f) ? 32512.f / am : 0.f;
  if (tid == 0) sc[r] = am * (1.f / 32512.f);
  int hb[8], lb[8];
#pragma unroll
  for (int e = 0; e < 8; ++e) {
    int n  = __float2int_rn(vv[e] * inv);
    int nh = (n + 128) >> 8;              // nh in [-127,127]
    hb[e] = nh & 0xff;
    lb[e] = (n - (nh << 8)) & 0xff;       // nl in [-128,127]
  }
  int2 hw, lw;
  hw.x = hb[0] | (hb[1] << 8) | (hb[2] << 16) | (hb[3] << 24);
  hw.y = hb[4] | (hb[5] << 8) | (hb[6] << 16) | (hb[7] << 24);
  lw.x = lb[0] | (lb[1] << 8) | (lb[2] << 16) | (lb[3] << 24);
  lw.y = lb[4] | (lb[5] << 8) | (lb[6] << 16) | (lb[7] << 24);
  *(int2*)(d + (size_t)r * 2048 + tid * 8)     = hw;
  *(int2*)(d + p + (size_t)r * 2048 + tid * 8) = lw;
}

// ---------------------------------------------------------------------------
// Int8 3-pass MFMA GEMM with optional split-K (grid z) + atomic epilogue.
// C (+)= sa[m]*sb[n] * (65536*acc_hh + 256*acc_cross), exact i32 accum.
// 128x128 tile, 4 waves, BK=64, double-buffered global_load_lds + counted
// vmcnt(8), linear LDS.  saUniform: single scalar scale for all A rows.
// ---------------------------------------------------------------------------
__global__ __launch_bounds__(256, 2) void gemm_i8(const signed char* __restrict__ Ag,
                                                  const signed char* __restrict__ Bg,
                                                  const float* __restrict__ sav,
                                                  const float* __restrict__ sbv,
                                                  float* __restrict__ C,
                                                  int M, int N, int K,
                                                  int kLen, int saUniform, int useAtomic) {
  __shared__ signed char Anh[2][128 * 64], Anl[2][128 * 64];
  __shared__ signed char Bnh[2][128 * 64], Bnl[2][128 * 64];

  const int tid  = threadIdx.x;
  const int lane = tid & 63;
  const int wid  = tid >> 6;
  const int wm   = (wid >> 1) << 6;       // 0 / 64
  const int wn   = (wid & 1) << 6;        // 0 / 64
  const int lo16 = lane & 15;
  const int hi4  = lane >> 4;
  const int m0   = blockIdx.y << 7;
  const int n0   = blockIdx.x << 7;
  const int kOff = blockIdx.z * kLen;
  const size_t MK = (size_t)M * K;        // lo-plane offset (bytes == elems)
  const size_t NK = (size_t)N * K;

  // staging: per plane 512 x 16B chunks; wave w: rows w*16+(lane>>2) and +64
  const int r0 = (wid << 4) + (lane >> 2);
  const int r1 = r0 + 64;
  const int cB = (lane & 3) << 4;         // byte col within 64B row-chunk
  const signed char* a0g = Ag + (size_t)(m0 + r0) * K + cB + kOff;
  const signed char* a1g = Ag + (size_t)(m0 + r1) * K + cB + kOff;
  const signed char* b0g = Bg + (size_t)(n0 + r0) * K + cB + kOff;
  const signed char* b1g = Bg + (size_t)(n0 + r1) * K + cB + kOff;
  const int o0 = wid << 10;               // wave-uniform LDS byte offsets
  const int o1 = (4 + wid) << 10;

  // fragment reads: row = lane&15 (+16*i), k-bytes = (lane>>4)*16
  int ra[4], rb[4];
#pragma unroll
  for (int i = 0; i < 4; ++i) {
    ra[i] = ((wm + i * 16 + lo16) << 6) + (hi4 << 4);
    rb[i] = ((wn + i * 16 + lo16) << 6) + (hi4 << 4);
  }

  i32x4 acc1[4][4], acc2[4][4];
  const i32x4 zi = {0, 0, 0, 0};
#pragma unroll
  for (int i = 0; i < 4; ++i)
#pragma unroll
    for (int j = 0; j < 4; ++j) { acc1[i][j] = zi; acc2[i][j] = zi; }

  // prologue: stage K-step 0 into buffer 0 (8 DMA per wave)
  gload16(a0g,      &Anh[0][o0]);
  gload16(a1g,      &Anh[0][o1]);
  gload16(a0g + MK, &Anl[0][o0]);
  gload16(a1g + MK, &Anl[0][o1]);
  gload16(b0g,      &Bnh[0][o0]);
  gload16(b1g,      &Bnh[0][o1]);
  gload16(b0g + NK, &Bnl[0][o0]);
  gload16(b1g + NK, &Bnl[0][o1]);

  int cur = 0;
  for (int k0 = 0; k0 < kLen; k0 += 64) {
    const bool more = (k0 + 64) < kLen;
    if (more) {
      const int nxt = cur ^ 1;
      const int kn  = k0 + 64;
      gload16(a0g + kn,      &Anh[nxt][o0]);
      gload16(a1g + kn,      &Anh[nxt][o1]);
      gload16(a0g + MK + kn, &Anl[nxt][o0]);
      gload16(a1g + MK + kn, &Anl[nxt][o1]);
      gload16(b0g + kn,      &Bnh[nxt][o0]);
      gload16(b1g + kn,      &Bnh[nxt][o1]);
      gload16(b0g + NK + kn, &Bnl[nxt][o0]);
      gload16(b1g + NK + kn, &Bnl[nxt][o1]);
      asm volatile("s_waitcnt vmcnt(8)" ::: "memory");
    } else {
      asm volatile("s_waitcnt vmcnt(0)" ::: "memory");
    }
    __builtin_amdgcn_s_barrier();
    __builtin_amdgcn_sched_barrier(0);

    i32x4 fah[4], fal[4], fbh[4], fbl[4];
#pragma unroll
    for (int i = 0; i < 4; ++i) {
      fah[i] = *(const i32x4*)&Anh[cur][ra[i]];
      fal[i] = *(const i32x4*)&Anl[cur][ra[i]];
      fbh[i] = *(const i32x4*)&Bnh[cur][rb[i]];
      fbl[i] = *(const i32x4*)&Bnl[cur][rb[i]];
    }
#pragma unroll
    for (int i = 0; i < 4; ++i)
#pragma unroll
      for (int j = 0; j < 4; ++j) {
        acc1[i][j] = __builtin_amdgcn_mfma_i32_16x16x64_i8(fah[i], fbh[j], acc1[i][j], 0, 0, 0);
        acc2[i][j] = __builtin_amdgcn_mfma_i32_16x16x64_i8(fah[i], fbl[j], acc2[i][j], 0, 0, 0);
        acc2[i][j] = __builtin_amdgcn_mfma_i32_16x16x64_i8(fal[i], fbh[j], acc2[i][j], 0, 0, 0);
      }

    __builtin_amdgcn_sched_barrier(0);
    __builtin_amdgcn_s_barrier();
    asm volatile("" ::: "memory");
    cur ^= 1;
  }

  // epilogue: D col = lane&15, row = (lane>>4)*4 + reg; dequant with scales
  const float saU = saUniform ? sav[0] : 0.f;
#pragma unroll
  for (int i = 0; i < 4; ++i) {
    const int rowb = m0 + wm + i * 16 + (hi4 << 2);
    float sa0, sa1, sa2, sa3;
    if (saUniform) { sa0 = sa1 = sa2 = sa3 = saU; }
    else { sa0 = sav[rowb]; sa1 = sav[rowb + 1]; sa2 = sav[rowb + 2]; sa3 = sav[rowb + 3]; }
#pragma unroll
    for (int j = 0; j < 4; ++j) {
      const int col = n0 + wn + j * 16 + lo16;
      const float sb = sbv[col];
      float* cp = C + (size_t)rowb * N + col;
      float v0 = fmaf(65536.f, (float)acc1[i][j][0], 256.f * (float)acc2[i][j][0]) * sa0 * sb;
      float v1 = fmaf(65536.f, (float)acc1[i][j][1], 256.f * (float)acc2[i][j][1]) * sa1 * sb;
      float v2 = fmaf(65536.f, (float)acc1[i][j][2], 256.f * (float)acc2[i][j][2]) * sa2 * sb;
      float v3 = fmaf(65536.f, (float)acc1[i][j][3], 256.f * (float)acc2[i][j][3]) * sa3 * sb;
      if (useAtomic) {
        atomicAdd(cp, v0);
        atomicAdd(cp + (size_t)N, v1);
        atomicAdd(cp + (size_t)2 * N, v2);
        atomicAdd(cp + (size_t)3 * N, v3);
      } else {
        cp[0]           = v0;
        cp[(size_t)N]   = v1;
        cp[(size_t)2*N] = v2;
        cp[(size_t)3*N] = v3;
      }
    }
  }
}

// ---------------------------------------------------------------------------
// rope2: RoPE + bf16 operand assembly; V-section also computes per-block
// amax|v| -> vamax[65] (for attention's conservative o-quant scale).
// ---------------------------------------------------------------------------
#define RB_Q  4096
#define RB_K  1024
#define RB_KE 64
#define RB_V  65

__global__ __launch_bounds__(256) void rope2(const float* __restrict__ qkv,
                                             const float* __restrict__ cosb,
                                             const float* __restrict__ sinb,
                                             const float* __restrict__ ksink,
                                             const float* __restrict__ vsink,
                                             unsigned short* __restrict__ qb,
                                             unsigned short* __restrict__ kb,
                                             unsigned short* __restrict__ vtb,
                                             float* __restrict__ vamax) {
  __shared__ unsigned short tl[512 * 33];
  __shared__ float vred[4];
  const int bid = blockIdx.x, tid = threadIdx.x;
  if (bid < RB_Q) {
    int idx = bid * 256 + tid;            // 1,048,576: (t, h, dp/2)
    int t = idx >> 9, rem = idx & 511;
    int h = rem >> 5, dp = (rem & 31) << 1;
    int g = h >> 2, qi = h & 3;
    const float* src = qkv + (size_t)t * 3072 + g * 768 + qi * 128;
    float2 x1 = *(const float2*)(src + dp);
    float2 x2 = *(const float2*)(src + 64 + dp);
    float2 c  = *(const float2*)(cosb + t * 64 + dp);
    float2 s  = *(const float2*)(sinb + t * 64 + dp);
    ushort2 o1 = { f2bf(x1.x * c.x - x2.x * s.x), f2bf(x1.y * c.y - x2.y * s.y) };
    ushort2 o2 = { f2bf(x1.x * s.x + x2.x * c.x), f2bf(x1.y * s.y + x2.y * c.y) };
    *(ushort2*)(qb + (size_t)t * 2048 + h * 128 + dp)      = o1;
    *(ushort2*)(qb + (size_t)t * 2048 + h * 128 + 64 + dp) = o2;
  } else if (bid < RB_Q + RB_K) {
    int idx = (bid - RB_Q) * 256 + tid;   // 262,144: (t, g, dp/2)
    int t = idx >> 7, rem = idx & 127;
    int g = rem >> 5, dp = (rem & 31) << 1;
    const float* src = qkv + (size_t)t * 3072 + g * 768 + 512;
    float2 x1 = *(const float2*)(src + dp);
    float2 x2 = *(const float2*)(src + 64 + dp);
    float2 c  = *(const float2*)(cosb + t * 64 + dp);
    float2 s  = *(const float2*)(sinb + t * 64 + dp);
    ushort2 o1 = { f2bf(x1.x * c.x - x2.x * s.x), f2bf(x1.y * c.y - x2.y * s.y) };
    ushort2 o2 = { f2bf(x1.x * s.x + x2.x * c.x), f2bf(x1.y * s.y + x2.y * c.y) };
    size_t base = (size_t)(t + 1) * 512 + g * 128 + dp;
    *(ushort2*)(kb + base)      = o1;
    *(ushort2*)(kb + base + 64) = o2;
  } else if (bid < RB_Q + RB_K + RB_KE) {
    int idx = (bid - RB_Q - RB_K) * 256 + tid;   // 16,384: sink + pads
    int jj = idx >> 9, c = idx & 511;
    if (jj == 0) kb[c] = f2bf(ksink[c]);
    else         kb[(size_t)(2048 + jj) * 512 + c] = 0;
  } else {
    int b  = bid - RB_Q - RB_K - RB_KE;   // 0..64, j-tile of 32
    int j0 = b << 5;
    float am = 0.f;
#pragma unroll 4
    for (int st = 0; st < 64; ++st) {
      int id = st * 256 + tid;            // 16,384 = 32 j x 512 gd
      int jj = id >> 9, c = id & 511;
      int j = j0 + jj;
      float val;
      if (j == 0)          val = vsink[c];
      else if (j <= T_SEQ) val = qkv[(size_t)(j - 1) * 3072 + (c >> 7) * 768 + 640 + (c & 127)];
      else                 val = 0.f;
      am = fmaxf(am, fabsf(val));
      tl[c * 33 + jj] = f2bf(val);
    }
#pragma unroll
    for (int o = 1; o <= 32; o <<= 1) am = fmaxf(am, __shfl_xor(am, o, 64));
    if ((tid & 63) == 0) vred[tid >> 6] = am;
    __syncthreads();
    if (tid == 0)
      vamax[b] = fmaxf(fmaxf(vred[0], vred[1]), fmaxf(vred[2], vred[3]));
#pragma unroll 4
    for (int st = 0; st < 32; ++st) {
      int id = st * 256 + tid;            // 8,192 = 512 rows x 16 jp-pairs
      int row = id >> 4, jp = (id & 15) << 1;
      ushort2 w = { tl[row * 33 + jp], tl[row * 33 + jp + 1] };
      *(ushort2*)(vtb + (size_t)row * JP + j0 + jp) = w;
    }
  }
}

// ---------------------------------------------------------------------------
// MFMA flash attention with per-block LDS K/V staging (double-buffered).
// Output: int16-split i8 planes with a CONSERVATIVE UNIFORM scale
// (|o| <= amax|v| since o is a convex combination of v rows); scale written
// for gemm_i8's saUniform path.  Inner math unchanged (harness-verified).
// ---------------------------------------------------------------------------
#define KSTR 136
#define VSTR 40

__global__ __launch_bounds__(512) void attn_mfma_bf16(const unsigned short* __restrict__ qb,
                                                      const unsigned short* __restrict__ kb,
                                                      const unsigned short* __restrict__ vtb,
                                                      signed char* __restrict__ ops,
                                                      const float* __restrict__ vamax,
                                                      float* __restrict__ s_oq) {
  __shared__ unsigned short Kl[2][32 * KSTR];   // 2 x 8704 B
  __shared__ unsigned short Vl[2][128 * VSTR];  // 2 x 10240 B

  const int bid  = blockIdx.x;
  const int tid  = threadIdx.x;
  const int tile = bid >> 2;              // 0..63 (32-row q-tiles)
  const int g    = bid & 3;
  const int t0b  = tile << 5;
  const int wv   = tid >> 6;
  const int hq   = wv & 3;
  const int sub  = wv >> 2;               // q-subtile within block
  const int h    = g * 4 + hq;
  const int lane = tid & 63;
  const int lo   = lane & 15;
  const int hi   = lane >> 4;
  const int t0w  = t0b + (sub << 4);
  const int t    = t0w + lo;              // this lane's q row

  // conservative o-quant scale from rope2's 65 per-block V maxima
  float vam = 0.f;
  for (int i = lane; i < 65; i += 64) vam = fmaxf(vam, vamax[i]);
#pragma unroll
  for (int o = 1; o <= 32; o <<= 1) vam = fmaxf(vam, __shfl_xor(vam, o, 64));
  const float s_eff = vam * 1.00390625f;  // margin for bf16 round-up
  const float invq  = (vam > 1e-30f) ? 32512.f / s_eff : 0.f;
  if (bid == 0 && tid == 0) *s_oq = s_eff * (1.f / 32512.f);

  // staging map: K: thread -> (local row sj, col sc); V: (d-row svd, col svj)
  const int sj   = tid >> 4;              // 0..31
  const int sc   = (tid & 15) << 3;       // 0,8,...,120
  const int kphi = ((((sj & 7) << 2) | (sj >> 3))) * KSTR + sc;
  const int svd  = tid >> 2;              // 0..127
  const int svj  = (tid & 3) << 3;        // 0,8,16,24
  const int vdst = svd * VSTR + svj;
  const unsigned short* ksrc = kb  + (size_t)sj * 512 + g * 128 + sc;
  const unsigned short* vsrc = vtb + (size_t)(g * 128 + svd) * JP + svj;

  // Q fragment (B operand of QK): lane holds q[t][d0*32 + 8*hi + e]
  short8 qfrag[4];
  {
    const unsigned short* qp = qb + (size_t)t * 2048 + h * 128 + (hi << 3);
#pragma unroll
    for (int d0 = 0; d0 < 4; ++d0) qfrag[d0] = *(const short8*)(qp + d0 * 32);
  }

  f32x4 acc[8];
  const f32x4 z4 = {0.f, 0.f, 0.f, 0.f};
#pragma unroll
  for (int dt = 0; dt < 8; ++dt) acc[dt] = z4;

  float m = -1e4f, l = 0.f;               // per-lane partial stats

  int jlo = t0b - 1022; if (jlo < 0) jlo = 0;
  const int jb0  = jlo & ~31;
  const int jmax = t0b + 32;              // largest valid j = (t0b+31)+1
  const int nch  = ((jmax - jb0) >> 5) + 1;

  const int klA = (((lo & 3) << 2) | (lo >> 2)) * KSTR + (hi << 3);

  // prologue: stage chunk 0
  uint4 kreg = *(const uint4*)(ksrc + (size_t)jb0 * 512);
  uint4 vreg = *(const uint4*)(vsrc + jb0);
  *(uint4*)&Kl[0][kphi] = kreg;
  *(uint4*)&Vl[0][vdst] = vreg;
  __syncthreads();

  int bsel = 0;
  for (int ci = 0; ci < nch; ++ci) {
    const int jb = jb0 + (ci << 5);
    const bool more = (ci + 1 < nch);
    if (more) {                            // issue next-chunk loads early
      const int jn = jb + 32;
      kreg = *(const uint4*)(ksrc + (size_t)jn * 512);
      vreg = *(const uint4*)(vsrc + jn);
    }

    // ---- QK^T: two 16x16 S^T tiles over K=128 (4 d-chunks), from LDS
    const unsigned short* Kb = &Kl[bsel][0];
    f32x4 sa = z4, sb = z4;
#pragma unroll
    for (int d0 = 0; d0 < 4; ++d0) {
      short8 ka  = *(const short8*)(Kb + klA + d0 * 32);
      short8 kB2 = *(const short8*)(Kb + klA + 16 * KSTR + d0 * 32);
      sa = __builtin_amdgcn_mfma_f32_16x16x32_bf16(ka,  qfrag[d0], sa, 0, 0, 0);
      sb = __builtin_amdgcn_mfma_f32_16x16x32_bf16(kB2, qfrag[d0], sb, 0, 0, 0);
    }

    float z[8];
    const int jbase = jb + (hi << 3);
    const bool interior = (jb >= t0w - 1007) && (jb <= t0w - 30);
    if (interior) {
#pragma unroll
      for (int r = 0; r < 4; ++r) { z[r] = sa[r] * SL_F; z[r + 4] = sb[r] * SL_F; }
    } else {
#pragma unroll
      for (int r = 0; r < 8; ++r) {
        float sv = (r < 4) ? sa[r] : sb[r - 4];
        int j = jbase + r;
        bool valid = (j <= t + 1) && (j >= t - 1022);
        z[r] = valid ? sv * SL_F : -1e30f;
      }
    }

    float lmax = fmaxf(fmaxf(fmaxf(z[0], z[1]), fmaxf(z[2], z[3])),
                       fmaxf(fmaxf(z[4], z[5]), fmaxf(z[6], z[7])));
    if (!__all(lmax <= m + THR_L2)) {
      float cm = lmax;
      cm = fmaxf(cm, __shfl_xor(cm, 16, 64));
      cm = fmaxf(cm, __shfl_xor(cm, 32, 64));
      float mn = fmaxf(m, cm);
      float a  = exp2f(m - mn);
      l *= a;
#pragma unroll
      for (int dt = 0; dt < 8; ++dt) acc[dt] *= a;
      m = mn;
    }

    float p[8];
#pragma unroll
    for (int r = 0; r < 8; ++r) { p[r] = exp2f(z[r] - m); l += p[r]; }

    short8 pfrag;
#pragma unroll
    for (int e = 0; e < 8; ++e) pfrag[e] = (short)f2bf(p[e]);

    // ---- PV: O^T += V^T * P^T  (8 d-tiles of 16), from LDS
    const unsigned short* Vb = &Vl[bsel][0];
#pragma unroll
    for (int dt = 0; dt < 8; ++dt) {
      short8 vf = *(const short8*)(Vb + (dt * 16 + lo) * VSTR + (hi << 3));
      acc[dt] = __builtin_amdgcn_mfma_f32_16x16x32_bf16(vf, pfrag, acc[dt], 0, 0, 0);
    }

    if (more) {                            // write next chunk, flip buffers
      *(uint4*)&Kl[bsel ^ 1][kphi] = kreg;
      *(uint4*)&Vl[bsel ^ 1][vdst] = vreg;
      __syncthreads();
      bsel ^= 1;
    }
  }

  float lt = l;
  lt += __shfl_xor(lt, 16, 64);
  lt += __shfl_xor(lt, 32, 64);
  const float inv = 1.f / lt;

  // epilogue: int16-split i8 planes (uniform scale), same element mapping
  const size_t elem = (size_t)t * 2048 + h * 128 + (hi << 2);
#pragma unroll
  for (int dt = 0; dt < 8; ++dt) {
    f32x4 o4 = acc[dt] * inv;
    int hb[4], lb[4];
#pragma unroll
    for (int e = 0; e < 4; ++e) {
      int n  = __float2int_rn(o4[e] * invq);
      int nh = (n + 128) >> 8;
      hb[e] = nh & 0xff;
      lb[e] = (n - (nh << 8)) & 0xff;
    }
    int hw = hb[0] | (hb[1] << 8) | (hb[2] << 16) | (hb[3] << 24);
    int lw = lb[0] | (lb[1] << 8) | (lb[2] << 16) | (lb[3] << 24);
    *(int*)(ops + elem + dt * 16)           = hw;
    *(int*)(ops + 4194304 + elem + dt * 16) = lw;
  }
}

extern "C" void kernel_launch(void* const* d_in, const int* in_sizes, int n_in,
                              void* d_out, int out_size, void* d_ws, size_t ws_size,
                              hipStream_t stream) {
  const float* x     = (const float*)d_in[0];   // (2048, 2048) f32
  const float* cosb  = (const float*)d_in[1];   // (2048, 64)   f32
  const float* sinb  = (const float*)d_in[2];   // (2048, 64)   f32
  const float* Wa    = (const float*)d_in[3];   // (3072, 2048) f32
  const float* Wp    = (const float*)d_in[4];   // (2048, 2048) f32
  const float* ksink = (const float*)d_in[5];   // (512,)       f32
  const float* vsink = (const float*)d_in[6];   // (512,)       f32
  float* y = (float*)d_out;                     // (2048, 2048) f32

  // Workspace (peak ~55.2 MB; stream-serial stages):
  //  [0,        25165824): qkv f32 (st2-3) | ops i8 planes [0,8388608) (st4-5)
  //  [25165824, 34214432): x planes (st1-2) | qb bf16 (st3-4)
  //  [34214432, 46797344): Wa planes (st1-2) | kb [34214432,36344352) +
  //                        vtb [36344352,38474272) (st3-4)
  //  [46797344, 55185952): Wp planes (st1-5)
  //  [55185952, +): scales s_x, s_wa, s_wp, vamax[65], s_oq
  char* ws = (char*)d_ws;
  float*          qkv = (float*)ws;
  signed char*    ops = (signed char*)ws;
  signed char*    xs  = (signed char*)(ws + 25165824);
  unsigned short* qb  = (unsigned short*)(ws + 25165824);
  signed char*    was = (signed char*)(ws + 34214432);
  unsigned short* kbb = (unsigned short*)(ws + 34214432);
  unsigned short* vtb = (unsigned short*)(ws + 36344352);
  signed char*    wps = (signed char*)(ws + 46797344);
  float*          s_x   = (float*)(ws + 55185952);
  float*          s_wa  = (float*)(ws + 55194144);
  float*          s_wp  = (float*)(ws + 55206432);
  float*          vamax = (float*)(ws + 55214624);
  float*          s_oq  = (float*)(ws + 55215136);

  // 0. zero y (split-K GEMM2 accumulates atomically)
  hipMemsetAsync(y, 0, out_size, stream);
  // 1. quantize x, Wa, Wp (per-row int16 -> i8 planes + scales), one launch
  quant3<<<7168, 256, 0, stream>>>(x, xs, s_x, Wa, was, s_wa, Wp, wps, s_wp);
  // 2. qkv = x @ Wa^T  (int8 3-pass MFMA)
  gemm_i8<<<dim3(24, 16, 1), 256, 0, stream>>>(xs, was, s_x, s_wa, qkv,
                                               2048, 3072, 2048, 2048, 0, 0);
  // 3. RoPE + operand assembly + V amax
  rope2<<<RB_Q + RB_K + RB_KE + RB_V, 256, 0, stream>>>(qkv, cosb, sinb, ksink, vsink,
                                                        qb, kbb, vtb, vamax);
  // 4. MFMA flash attention (writes i8 o-planes + uniform scale)
  attn_mfma_bf16<<<256, 512, 0, stream>>>(qb, kbb, vtb, ops, vamax, s_oq);
  // 5. y += o @ Wp^T  (int8 3-pass MFMA, split-K=2, atomic accumulate)
  gemm_i8<<<dim3(16, 16, 2), 256, 0, stream>>>(ops, wps, s_oq, s_wp, y,
                                               2048, 2048, 2048, 1024, 1, 1);
}